// Round 7
// baseline (453.814 us; speedup 1.0000x reference)
//
#include <hip/hip_runtime.h>

#define NN 8192
#define DD 256
#define FF 128
#define BB 4096
#define NSPLIT 16
#define KCHUNK (NN / NSPLIT)   // 512 keys per split-K chunk
#define KVBLK 32
#define NITER (KCHUNK / KVBLK) // 16 key-tiles per chunk

typedef unsigned short ushortT;
typedef __attribute__((ext_vector_type(8))) short bf16x8;
typedef __attribute__((ext_vector_type(4))) float f32x4;

__device__ __forceinline__ ushortT f2bf(float f) {   // fp32 -> bf16 RNE
  unsigned u = __float_as_uint(f);
  return (ushortT)((u + 0x7FFFu + ((u >> 16) & 1u)) >> 16);
}
__device__ __forceinline__ float bf2f(ushortT h) {
  return __uint_as_float(((unsigned)h) << 16);
}

// ---------------- unique(x) compaction ----------------

__global__ __launch_bounds__(256) void init_kernel(int* flags, int* cnt) {
  int i = blockIdx.x * 256 + threadIdx.x;
  flags[i] = 0;
  if (i == 0) *cnt = 0;
}

__global__ __launch_bounds__(256) void scatter_kernel(const int* __restrict__ x, int* flags) {
  int b = blockIdx.x * 256 + threadIdx.x;
  flags[x[b]] = 1;
}

__global__ __launch_bounds__(256) void compact_kernel(const int* __restrict__ flags, int* cnt,
                                                      int* list, int* slot) {
  int i = blockIdx.x * 256 + threadIdx.x;
  if (flags[i]) {
    int pos = atomicAdd(cnt, 1);
    list[pos] = i;
    slot[i] = pos;
  }
}

// ---------------- pack adj rows of unique slots into bitmasks ----------------

__global__ __launch_bounds__(256) void pack_kernel(const int* __restrict__ adj,
                                                   const int* __restrict__ list,
                                                   const int* __restrict__ cntp,
                                                   unsigned* __restrict__ pk) {
  const int s = blockIdx.x >> 2;
  const int kc = (blockIdx.x & 3) * 2048;
  if (s >= *cntp) return;                    // uniform per block
  const int w = threadIdx.x >> 6, l = threadIdx.x & 63;
  const int* base = adj + (size_t)list[s] * NN + kc + w * 512;
  unsigned long long* dst = (unsigned long long*)(pk + s * 256 + (kc >> 5) + w * 16);
#pragma unroll
  for (int i = 0; i < 8; ++i) {
    unsigned long long b = __ballot(base[i * 64 + l] > 0);  // bit l = key ...+i*64+l
    if (l == 0) dst[i] = b;
  }
}

// ---------------- Wh = embedding @ W, emitted as bf16 hi/lo split ----------------

__global__ __launch_bounds__(256) void wh_kernel(const float* __restrict__ emb,
                                                 const float* __restrict__ W,
                                                 ushortT* __restrict__ Whh,
                                                 ushortT* __restrict__ Whl) {
  __shared__ float Es[32 * 65];
  __shared__ float Ws[64 * 128];
  const int t = threadIdx.x;
  const int r0 = blockIdx.x * 32;
  const int rg = t >> 5;
  const int cg = t & 31;
  float4 acc[4] = {{0,0,0,0},{0,0,0,0},{0,0,0,0},{0,0,0,0}};
  for (int kc = 0; kc < DD; kc += 64) {
    __syncthreads();
    for (int i = 0; i < 8; ++i) {
      int idx = t + 256 * i;
      int r = idx >> 6, k = idx & 63;
      Es[r * 65 + k] = emb[(r0 + r) * DD + kc + k];
    }
    for (int i = 0; i < 8; ++i) {
      int idx = t + 256 * i;
      int kr = idx >> 5, c4 = (idx & 31) * 4;
      *(float4*)&Ws[kr * 128 + c4] = *(const float4*)&W[(kc + kr) * 128 + c4];
    }
    __syncthreads();
    for (int k = 0; k < 64; ++k) {
      float4 b = *(const float4*)&Ws[k * 128 + cg * 4];
#pragma unroll
      for (int i = 0; i < 4; ++i) {
        float a = Es[(rg * 4 + i) * 65 + k];
        acc[i].x += a * b.x; acc[i].y += a * b.y;
        acc[i].z += a * b.z; acc[i].w += a * b.w;
      }
    }
  }
#pragma unroll
  for (int i = 0; i < 4; ++i) {
    int row = r0 + rg * 4 + i;
    float v[4] = {acc[i].x, acc[i].y, acc[i].z, acc[i].w};
    ushort4 hh, ll;
    ushortT* hp = (ushortT*)&hh;
    ushortT* lp = (ushortT*)&ll;
#pragma unroll
    for (int k = 0; k < 4; ++k) {
      ushortT h = f2bf(v[k]);
      hp[k] = h;
      lp[k] = f2bf(v[k] - bf2f(h));
    }
    *(ushort4*)&Whh[row * FF + cg * 4] = hh;
    *(ushort4*)&Whl[row * FF + cg * 4] = ll;
  }
}

// ---------------- WhT = Whh^T (128 x 8192), 64x64 tiles (256 blocks) ----------------

__global__ __launch_bounds__(256) void transpose_kernel(const ushortT* __restrict__ A,
                                                        ushortT* __restrict__ At) {
  __shared__ ushortT tile[64 * 72];
  const int t = threadIdx.x;
  const int r0 = (blockIdx.x >> 1) * 64, c0 = (blockIdx.x & 1) * 64;
#pragma unroll
  for (int i = 0; i < 2; ++i) {
    int idx = t + 256 * i;
    int r = idx >> 3, cb = idx & 7;
    *(bf16x8*)&tile[r * 72 + ((cb ^ ((r >> 3) & 7)) * 8)] =
        *(const bf16x8*)&A[(size_t)(r0 + r) * FF + c0 + cb * 8];
  }
  __syncthreads();
#pragma unroll
  for (int i = 0; i < 2; ++i) {
    int idx = t + 256 * i;
    int f = idx >> 3, r8 = idx & 7;
    bf16x8 v;
#pragma unroll
    for (int u = 0; u < 8; ++u) {
      int row = r8 * 8 + u;
      v[u] = (short)tile[row * 72 + (((f >> 3) ^ ((row >> 3) & 7)) * 8) + (f & 7)];
    }
    *(bf16x8*)&At[(size_t)(c0 + f) * NN + r0 + r8 * 8] = v;
  }
}

// ---------------- MFMA flash attention: r3 structure, KVBLK=32, 12 waves/CU ----------------
// Latency-convoy hypothesis: r0/r3/r4/r6 all idle ~90% at 8 waves/CU because every
// resident wave hits the same barrier + staged-load vmcnt together. Fix = more
// independent blocks per CU. This is round-3's exact verified structure (16x16 MFMA,
// A=Q B=K, Ps LDS round-trip, staged K+V, async-stage split, 2 barriers/iter) with the
// key tile halved to 32: LDS = Kh 8K + Kl 8K + Vs 8K + Ps 5K + nid = ~30 KB and ~135
// VGPR -> launch_bounds(256,3) = 3 blocks/CU (12 waves, 1.5x r4). 816 active blocks
// ~ 3.2/CU. All swizzles are the KVBLK-rescale of r3's verified ones; MFMA term set
// (qh*kh, ql*kh, qh*kl), f2bf P quantization, and split-K merge unchanged -> absmax
// must stay 0.001953125.
// Layouts: A[m=lane&15][k=quad*8+j]; B[k=quad*8+j][n=lane&15]; C/D row=quad*4+reg, col=lane&15.

__global__ __launch_bounds__(256, 3) void attn_kernel(
    const ushortT* __restrict__ Whh, const ushortT* __restrict__ Whl,
    const ushortT* __restrict__ WhT, const unsigned* __restrict__ pk,
    const int* __restrict__ list, const int* __restrict__ cntp,
    float* __restrict__ Opart, float* __restrict__ mpart, float* __restrict__ lpart) {
  __shared__ short Kh[KVBLK * 128];
  __shared__ short Kl[KVBLK * 128];
  __shared__ short Vs[128 * KVBLK];      // [feat][key], chunk-XOR-swizzled
  __shared__ short Ps[4][16 * 40];       // per-wave P rows (16 q x 32 keys, pad 40)
  __shared__ int nid[64];

  const int cnt = *cntp;
  const int qblk = blockIdx.x >> 4, chunk = blockIdx.x & 15;
  const int q0 = qblk * 64;
  if (q0 >= cnt) return;                 // uniform: whole block exits

  const int t = threadIdx.x;
  if (t < 64) nid[t] = list[min(q0 + t, cnt - 1)];  // tail rows dup cnt-1
  __syncthreads();

  const int w = t >> 6, l = t & 63, quad = l >> 4, c = l & 15;

  // Q fragments in registers for the whole K loop (A-operand: row = c)
  const size_t qr = (size_t)nid[w * 16 + c] * FF;
  bf16x8 qh[4], ql[4];
#pragma unroll
  for (int ks = 0; ks < 4; ++ks) {
    qh[ks] = *(const bf16x8*)(Whh + qr + ks * 32 + quad * 8);
    ql[ks] = *(const bf16x8*)(Whl + qr + ks * 32 + quad * 8);
  }
  int prow[4];
#pragma unroll
  for (int r = 0; r < 4; ++r) prow[r] = min(q0 + w * 16 + quad * 4 + r, cnt - 1);

  float m[4], lr[4];
#pragma unroll
  for (int r = 0; r < 4; ++r) { m[r] = -1e30f; lr[r] = 0.f; }
  f32x4 O[8] = {{0,0,0,0},{0,0,0,0},{0,0,0,0},{0,0,0,0},
                {0,0,0,0},{0,0,0,0},{0,0,0,0},{0,0,0,0}};

  const int kt0 = chunk * KCHUNK;

  // prologue: stage tile 0 (K hi/lo 32x128 + V 128x32) into LDS
  bf16x8 sgh[2], sgl[2], sgv[2];
  {
    const ushortT* gh = Whh + (size_t)kt0 * FF;
    const ushortT* gl = Whl + (size_t)kt0 * FF;
#pragma unroll
    for (int i = 0; i < 2; ++i) {
      int idx = t + 256 * i;
      sgh[i] = *(const bf16x8*)(gh + idx * 8);
      sgl[i] = *(const bf16x8*)(gl + idx * 8);
      int vr = idx >> 2, vcb = idx & 3;
      sgv[i] = *(const bf16x8*)(WhT + (size_t)vr * NN + kt0 + vcb * 8);
    }
#pragma unroll
    for (int i = 0; i < 2; ++i) {
      int idx = t + 256 * i;
      int r = idx >> 4, cb = idx & 15;
      int off = r * 128 + ((cb ^ (r & 7)) * 8);
      *(bf16x8*)&Kh[off] = sgh[i];
      *(bf16x8*)&Kl[off] = sgl[i];
      int vr = idx >> 2, vcb = idx & 3;
      *(bf16x8*)&Vs[vr * KVBLK + ((vcb ^ (vr & 3)) * 8)] = sgv[i];
    }
  }
  __syncthreads();

  for (int it = 0; it < NITER; ++it) {
    const int kt = kt0 + it * KVBLK;

    // ---- issue next K/V-tile global loads into regs (land during compute) ----
    if (it + 1 < NITER) {
      const ushortT* gh = Whh + (size_t)(kt + KVBLK) * FF;
      const ushortT* gl = Whl + (size_t)(kt + KVBLK) * FF;
#pragma unroll
      for (int i = 0; i < 2; ++i) {
        int idx = t + 256 * i;
        sgh[i] = *(const bf16x8*)(gh + idx * 8);
        sgl[i] = *(const bf16x8*)(gl + idx * 8);
        int vr = idx >> 2, vcb = idx & 3;
        sgv[i] = *(const bf16x8*)(WhT + (size_t)vr * NN + (kt + KVBLK) + vcb * 8);
      }
    }

    // ---- mask words: 32 bits per q-row (keys kt..kt+31) ----
    unsigned m32[4];
#pragma unroll
    for (int r = 0; r < 4; ++r) m32[r] = pk[(size_t)prow[r] * 256 + (kt >> 5)];

    // ---- S = Q.K^T over 2 key-16 tiles, 3-term hi/lo, K from LDS ----
    f32x4 sacc[2];
#pragma unroll
    for (int nt = 0; nt < 2; ++nt) {
      const int rb = (nt * 16 + c) * 128;
      f32x4 a = {0, 0, 0, 0};
#pragma unroll
      for (int ks = 0; ks < 4; ++ks) {
        const int off = rb + (((ks * 4 + quad) ^ (c & 7)) * 8);
        bf16x8 bh = *(const bf16x8*)&Kh[off];
        bf16x8 bl = *(const bf16x8*)&Kl[off];
        a = __builtin_amdgcn_mfma_f32_16x16x32_bf16(qh[ks], bh, a, 0, 0, 0);
        a = __builtin_amdgcn_mfma_f32_16x16x32_bf16(ql[ks], bh, a, 0, 0, 0);
        a = __builtin_amdgcn_mfma_f32_16x16x32_bf16(qh[ks], bl, a, 0, 0, 0);
      }
      sacc[nt] = a;
    }

    // ---- in-wave masked online softmax ----
    float rmax[4];
#pragma unroll
    for (int r = 0; r < 4; ++r) {
      float v = -1e30f;
#pragma unroll
      for (int nt = 0; nt < 2; ++nt) {
        unsigned bit = (m32[r] >> (nt * 16 + c)) & 1u;
        v = fmaxf(v, bit ? sacc[nt][r] : -1e30f);
      }
      rmax[r] = v;
    }
#pragma unroll
    for (int mk = 1; mk <= 8; mk <<= 1)
#pragma unroll
      for (int r = 0; r < 4; ++r) rmax[r] = fmaxf(rmax[r], __shfl_xor(rmax[r], mk, 16));
    float sc[4], psum[4];
#pragma unroll
    for (int r = 0; r < 4; ++r) {
      float nm = fmaxf(m[r], rmax[r]);
      sc[r] = __expf(m[r] - nm);
      m[r] = nm;
      psum[r] = 0.f;
    }
#pragma unroll
    for (int nt = 0; nt < 2; ++nt)
#pragma unroll
      for (int r = 0; r < 4; ++r) {
        unsigned bit = (m32[r] >> (nt * 16 + c)) & 1u;
        float p = bit ? __expf(sacc[nt][r] - m[r]) : 0.f;
        ushortT pb = f2bf(p);
        Ps[w][(quad * 4 + r) * 40 + nt * 16 + c] = (short)pb;
        psum[r] += bf2f(pb);
      }
#pragma unroll
    for (int mk = 1; mk <= 8; mk <<= 1)
#pragma unroll
      for (int r = 0; r < 4; ++r) psum[r] += __shfl_xor(psum[r], mk, 16);
#pragma unroll
    for (int r = 0; r < 4; ++r) lr[r] = lr[r] * sc[r] + psum[r];

    // ---- O rescale + PV (A = P from per-wave Ps, B = V from Vs LDS) ----
#pragma unroll
    for (int ft = 0; ft < 8; ++ft)
#pragma unroll
      for (int r = 0; r < 4; ++r) O[ft][r] *= sc[r];
    bf16x8 pa = *(const bf16x8*)&Ps[w][c * 40 + quad * 8];  // A[q=c][key=quad*8+j]
#pragma unroll
    for (int ft = 0; ft < 8; ++ft) {
      const int vrow = ft * 16 + c;
      const int voff = vrow * KVBLK + ((quad ^ (vrow & 3)) * 8);
      bf16x8 vb = *(const bf16x8*)&Vs[voff];
      O[ft] = __builtin_amdgcn_mfma_f32_16x16x32_bf16(pa, vb, O[ft], 0, 0, 0);
    }

    // ---- stage the prefetched tiles into LDS for next iter ----
    if (it + 1 < NITER) {
      __syncthreads();                   // all waves done reading Kh/Kl/Vs
#pragma unroll
      for (int i = 0; i < 2; ++i) {
        int idx = t + 256 * i;
        int r = idx >> 4, cb = idx & 15;
        int off = r * 128 + ((cb ^ (r & 7)) * 8);
        *(bf16x8*)&Kh[off] = sgh[i];
        *(bf16x8*)&Kl[off] = sgl[i];
        int vr = idx >> 2, vcb = idx & 3;
        *(bf16x8*)&Vs[vr * KVBLK + ((vcb ^ (vr & 3)) * 8)] = sgv[i];
      }
      __syncthreads();                   // buffers ready
    }
  }

  // ---- epilogue ----
  float* Op = Opart + (size_t)chunk * 4096 * FF;
#pragma unroll
  for (int ft = 0; ft < 8; ++ft)
#pragma unroll
    for (int r = 0; r < 4; ++r)
      Op[(size_t)(q0 + w * 16 + quad * 4 + r) * FF + ft * 16 + c] = O[ft][r];
  if (c == 0) {
#pragma unroll
    for (int r = 0; r < 4; ++r) {
      mpart[chunk * 4096 + q0 + w * 16 + quad * 4 + r] = m[r];
      lpart[chunk * 4096 + q0 + w * 16 + quad * 4 + r] = lr[r];
    }
  }
}

// ---------------- merge split-K partials, normalize, elu ----------------

__global__ __launch_bounds__(128) void combine_kernel(
    const float* __restrict__ Opart, const float* __restrict__ mpart,
    const float* __restrict__ lpart, const int* __restrict__ cntp,
    float* __restrict__ h) {
  const int r = blockIdx.x;
  if (r >= *cntp) return;                // junk rows never read downstream
  const int t = threadIdx.x;
  float mstar = -1e30f;
#pragma unroll
  for (int c = 0; c < NSPLIT; ++c) mstar = fmaxf(mstar, mpart[c * 4096 + r]);
  float lstar = 0.f, acc = 0.f;
#pragma unroll
  for (int c = 0; c < NSPLIT; ++c) {
    float wgt = __expf(mpart[c * 4096 + r] - mstar);
    lstar += wgt * lpart[c * 4096 + r];
    acc += wgt * Opart[((size_t)c * 4096 + r) * FF + t];
  }
  float v = acc / fmaxf(lstar, 1e-30f);
  h[r * FF + t] = v > 0.f ? v : expm1f(v);
}

// ---------------- gather by x, L2-normalize ----------------

__global__ __launch_bounds__(128) void out_kernel(const int* __restrict__ x,
                                                  const int* __restrict__ slot,
                                                  const float* __restrict__ h,
                                                  float* __restrict__ out) {
  const int b = blockIdx.x, t = threadIdx.x;
  const int s = slot[x[b]];
  float v = h[s * FF + t];
  float ss = v * v;
#pragma unroll
  for (int wd = 1; wd <= 32; wd <<= 1) ss += __shfl_xor(ss, wd);
  __shared__ float red[2];
  if ((t & 63) == 0) red[t >> 6] = ss;
  __syncthreads();
  float tot = red[0] + red[1];
  float scale = 1.f / fmaxf(sqrtf(tot), 1e-12f);
  out[b * FF + t] = v * scale;
}

// ---------------- launch ----------------

extern "C" void kernel_launch(void* const* d_in, const int* in_sizes, int n_in,
                              void* d_out, int out_size, void* d_ws, size_t ws_size,
                              hipStream_t stream) {
  const int*   x   = (const int*)d_in[0];
  const int*   adj = (const int*)d_in[1];
  const float* emb = (const float*)d_in[2];
  const float* W   = (const float*)d_in[3];
  float* out = (float*)d_out;

  char* base = (char*)d_ws;                              // ~44.6 MB total
  ushortT* Whh = (ushortT*)(base);                       //  0 .. 2 MB
  ushortT* Whl = (ushortT*)(base + 2097152);             //  2 .. 4 MB (dead after attn)
  float*   h   = (float*)(base + 2097152);               //  aliases Whl
  ushortT* WhT = (ushortT*)(base + 4194304);             //  4 .. 6 MB
  float* Opart = (float*)(base + 6291456);               //  6 .. 39.55 MB (16 chunks)
  float* mpart = (float*)(base + 39845888);
  float* lpart = (float*)(base + 40108032);
  unsigned* pk = (unsigned*)(base + 40370176);           //  4 MB packed adj bits
  int*   flags = (int*)(base + 44564480);
  int*   list  = (int*)(base + 44597248);
  int*   slot  = (int*)(base + 44613632);
  int*   cnt   = (int*)(base + 44646400);
  (void)in_sizes; (void)n_in; (void)out_size; (void)ws_size;

  hipLaunchKernelGGL(init_kernel,      dim3(NN / 256), dim3(256), 0, stream, flags, cnt);
  hipLaunchKernelGGL(scatter_kernel,   dim3(BB / 256), dim3(256), 0, stream, x, flags);
  hipLaunchKernelGGL(compact_kernel,   dim3(NN / 256), dim3(256), 0, stream, flags, cnt, list, slot);
  hipLaunchKernelGGL(pack_kernel,      dim3(4096 * 4), dim3(256), 0, stream, adj, list, cnt, pk);
  hipLaunchKernelGGL(wh_kernel,        dim3(NN / 32),  dim3(256), 0, stream, emb, W, Whh, Whl);
  hipLaunchKernelGGL(transpose_kernel, dim3((NN / 64) * 2), dim3(256), 0, stream, Whh, WhT);
  hipLaunchKernelGGL(attn_kernel,      dim3((BB / 64) * NSPLIT), dim3(256), 0, stream,
                     Whh, Whl, WhT, pk, list, cnt, Opart, mpart, lpart);
  hipLaunchKernelGGL(combine_kernel,   dim3(4096), dim3(128), 0, stream, Opart, mpart, lpart, cnt, h);
  hipLaunchKernelGGL(out_kernel,       dim3(BB),   dim3(128), 0, stream, x, slot, h, out);
}

// Round 8
// 434.965 us; speedup vs baseline: 1.0433x; 1.0433x over previous
//
#include <hip/hip_runtime.h>

#define NN 8192
#define DD 256
#define FF 128
#define BB 4096
#define NSPLIT 19
#define NTILES 128             // 8192 keys / 64

typedef unsigned short ushortT;
typedef __attribute__((ext_vector_type(8))) short bf16x8;
typedef __attribute__((ext_vector_type(4))) float f32x4;
typedef __attribute__((ext_vector_type(16))) float f32x16;

__device__ __forceinline__ ushortT f2bf(float f) {   // fp32 -> bf16 RNE
  unsigned u = __float_as_uint(f);
  return (ushortT)((u + 0x7FFFu + ((u >> 16) & 1u)) >> 16);
}
__device__ __forceinline__ float bf2f(ushortT h) {
  return __uint_as_float(((unsigned)h) << 16);
}

// ---------------- unique(x) compaction ----------------

__global__ __launch_bounds__(256) void init_kernel(int* flags, int* cnt) {
  int i = blockIdx.x * 256 + threadIdx.x;
  flags[i] = 0;
  if (i == 0) *cnt = 0;
}

__global__ __launch_bounds__(256) void scatter_kernel(const int* __restrict__ x, int* flags) {
  int b = blockIdx.x * 256 + threadIdx.x;
  flags[x[b]] = 1;
}

__global__ __launch_bounds__(256) void compact_kernel(const int* __restrict__ flags, int* cnt,
                                                      int* list, int* slot) {
  int i = blockIdx.x * 256 + threadIdx.x;
  if (flags[i]) {
    int pos = atomicAdd(cnt, 1);
    list[pos] = i;
    slot[i] = pos;
  }
}

// ---------------- pack adj rows of unique slots into bitmasks ----------------

__global__ __launch_bounds__(256) void pack_kernel(const int* __restrict__ adj,
                                                   const int* __restrict__ list,
                                                   const int* __restrict__ cntp,
                                                   unsigned* __restrict__ pk) {
  const int s = blockIdx.x >> 2;
  const int kc = (blockIdx.x & 3) * 2048;
  if (s >= *cntp) return;                    // uniform per block
  const int w = threadIdx.x >> 6, l = threadIdx.x & 63;
  const int* base = adj + (size_t)list[s] * NN + kc + w * 512;
  unsigned long long* dst = (unsigned long long*)(pk + s * 256 + (kc >> 5) + w * 16);
#pragma unroll
  for (int i = 0; i < 8; ++i) {
    unsigned long long b = __ballot(base[i * 64 + l] > 0);  // bit l = key ...+i*64+l
    if (l == 0) dst[i] = b;
  }
}

// ---------------- Wh = embedding @ W, emitted as bf16 hi/lo split ----------------

__global__ __launch_bounds__(256) void wh_kernel(const float* __restrict__ emb,
                                                 const float* __restrict__ W,
                                                 ushortT* __restrict__ Whh,
                                                 ushortT* __restrict__ Whl) {
  __shared__ float Es[32 * 65];
  __shared__ float Ws[64 * 128];
  const int t = threadIdx.x;
  const int r0 = blockIdx.x * 32;
  const int rg = t >> 5;
  const int cg = t & 31;
  float4 acc[4] = {{0,0,0,0},{0,0,0,0},{0,0,0,0},{0,0,0,0}};
  for (int kc = 0; kc < DD; kc += 64) {
    __syncthreads();
    for (int i = 0; i < 8; ++i) {
      int idx = t + 256 * i;
      int r = idx >> 6, k = idx & 63;
      Es[r * 65 + k] = emb[(r0 + r) * DD + kc + k];
    }
    for (int i = 0; i < 8; ++i) {
      int idx = t + 256 * i;
      int kr = idx >> 5, c4 = (idx & 31) * 4;
      *(float4*)&Ws[kr * 128 + c4] = *(const float4*)&W[(kc + kr) * 128 + c4];
    }
    __syncthreads();
    for (int k = 0; k < 64; ++k) {
      float4 b = *(const float4*)&Ws[k * 128 + cg * 4];
#pragma unroll
      for (int i = 0; i < 4; ++i) {
        float a = Es[(rg * 4 + i) * 65 + k];
        acc[i].x += a * b.x; acc[i].y += a * b.y;
        acc[i].z += a * b.z; acc[i].w += a * b.w;
      }
    }
  }
#pragma unroll
  for (int i = 0; i < 4; ++i) {
    int row = r0 + rg * 4 + i;
    float v[4] = {acc[i].x, acc[i].y, acc[i].z, acc[i].w};
    ushort4 hh, ll;
    ushortT* hp = (ushortT*)&hh;
    ushortT* lp = (ushortT*)&ll;
#pragma unroll
    for (int k = 0; k < 4; ++k) {
      ushortT h = f2bf(v[k]);
      hp[k] = h;
      lp[k] = f2bf(v[k] - bf2f(h));
    }
    *(ushort4*)&Whh[row * FF + cg * 4] = hh;
    *(ushort4*)&Whl[row * FF + cg * 4] = ll;
  }
}

// ---------------- WhT = Whh^T (128 x 8192), 64x64 tiles (256 blocks) ----------------

__global__ __launch_bounds__(256) void transpose_kernel(const ushortT* __restrict__ A,
                                                        ushortT* __restrict__ At) {
  __shared__ ushortT tile[64 * 72];
  const int t = threadIdx.x;
  const int r0 = (blockIdx.x >> 1) * 64, c0 = (blockIdx.x & 1) * 64;
#pragma unroll
  for (int i = 0; i < 2; ++i) {
    int idx = t + 256 * i;
    int r = idx >> 3, cb = idx & 7;
    *(bf16x8*)&tile[r * 72 + ((cb ^ ((r >> 3) & 7)) * 8)] =
        *(const bf16x8*)&A[(size_t)(r0 + r) * FF + c0 + cb * 8];
  }
  __syncthreads();
#pragma unroll
  for (int i = 0; i < 2; ++i) {
    int idx = t + 256 * i;
    int f = idx >> 3, r8 = idx & 7;
    bf16x8 v;
#pragma unroll
    for (int u = 0; u < 8; ++u) {
      int row = r8 * 8 + u;
      v[u] = (short)tile[row * 72 + (((f >> 3) ^ ((row >> 3) & 7)) * 8) + (f & 7)];
    }
    *(bf16x8*)&At[(size_t)(c0 + f) * NN + r0 + r8 * 8] = v;
  }
}

// ---------------- MFMA flash attention: round-4 exact (empirical best, 435.0 us) ----------
// Block = 256 thr = 4 waves, 128 q-rows (wave w: rows w*32..+31), chunk = NTILES/19 key-tiles.
// S^T = mfma32(A=K, B=Q): C col=lane&31 = q, row=(reg&3)+8*(reg>>2)+4*(lane>>5) = key.
// Each lane owns ONE q-column -> softmax fully in-lane + one shfl_xor(32). P stays in
// regs (bf16, f2bf RNE); one xor-32 word exchange builds PV B-frags. PV computes
// O^T = mfma32(A=V^T from Vs, B=P^T): O col = q -> per-lane sc rescale. K/V LDS-staged
// (async-stage split), XOR chunk swizzle. LDS = Kh 16K + Kl 16K + Vs 16K + nid = 49.7 KB.
// Null levers from r5-r7 (occupancy-3, XCD-pin, setprio, defer-max, KVBLK=32) removed —
// each measured 435 -> 450-454. MFMA term set (Kh*Qh, Kh*Ql, Kl*Qh) fixed.

__global__ __launch_bounds__(256, 2) void attn_kernel(
    const ushortT* __restrict__ Whh, const ushortT* __restrict__ Whl,
    const ushortT* __restrict__ WhT, const unsigned* __restrict__ pk,
    const int* __restrict__ list, const int* __restrict__ cntp,
    float* __restrict__ Opart, float* __restrict__ mpart, float* __restrict__ lpart) {
  __shared__ short Kh[64 * 128];
  __shared__ short Kl[64 * 128];
  __shared__ short Vs[128 * 64];         // [feat][key], chunk-XOR-swizzled
  __shared__ int nid[128];

  const int cnt = *cntp;
  const int qblk = blockIdx.x / NSPLIT, chunk = blockIdx.x % NSPLIT;
  const int q0 = qblk * 128;
  if (q0 >= cnt) return;                 // uniform: whole block exits

  const int t = threadIdx.x;
  if (t < 128) nid[t] = list[min(q0 + t, cnt - 1)];  // tail rows dup cnt-1
  __syncthreads();

  const int w = t >> 6, l = t & 63, h = l >> 5, lq = l & 31;

  // Q B-frags in registers: B[k=d=(h*8+j)+16*st][n=q=lq]
  const size_t qr = (size_t)nid[w * 32 + lq] * FF;
  bf16x8 qh[8], ql[8];
#pragma unroll
  for (int st = 0; st < 8; ++st) {
    qh[st] = *(const bf16x8*)(Whh + qr + st * 16 + h * 8);
    ql[st] = *(const bf16x8*)(Whl + qr + st * 16 + h * 8);
  }
  const int prow = min(q0 + w * 32 + lq, cnt - 1);

  float m = -1e30f, lr = 0.f;
  f32x16 O[4];
#pragma unroll
  for (int ft = 0; ft < 4; ++ft)
#pragma unroll
    for (int e = 0; e < 16; ++e) O[ft][e] = 0.f;

  const int ts = (chunk * NTILES) / NSPLIT;
  const int te = ((chunk + 1) * NTILES) / NSPLIT;

  // prologue: stage tile ts (K hi/lo + V) into LDS
  bf16x8 sgh[4], sgl[4], sgv[4];
  {
    const int kt0 = ts * 64;
    const ushortT* gh = Whh + (size_t)kt0 * FF;
    const ushortT* gl = Whl + (size_t)kt0 * FF;
#pragma unroll
    for (int i = 0; i < 4; ++i) {
      int idx = t + 256 * i;
      sgh[i] = *(const bf16x8*)(gh + idx * 8);
      sgl[i] = *(const bf16x8*)(gl + idx * 8);
      int vr = idx >> 3, vcb = idx & 7;
      sgv[i] = *(const bf16x8*)(WhT + (size_t)vr * NN + kt0 + vcb * 8);
    }
#pragma unroll
    for (int i = 0; i < 4; ++i) {
      int idx = t + 256 * i;
      int r = idx >> 4, cb = idx & 15;
      int off = r * 128 + ((cb ^ (r & 7)) * 8);
      *(bf16x8*)&Kh[off] = sgh[i];
      *(bf16x8*)&Kl[off] = sgl[i];
      int vr = idx >> 3, vcb = idx & 7;
      *(bf16x8*)&Vs[vr * 64 + ((vcb ^ (vr & 7)) * 8)] = sgv[i];
    }
  }
  __syncthreads();

  for (int it = ts; it < te; ++it) {
    const int kt = it * 64;

    // ---- issue next K/V-tile global loads into regs (land during compute) ----
    if (it + 1 < te) {
      const ushortT* gh = Whh + (size_t)(kt + 64) * FF;
      const ushortT* gl = Whl + (size_t)(kt + 64) * FF;
#pragma unroll
      for (int i = 0; i < 4; ++i) {
        int idx = t + 256 * i;
        sgh[i] = *(const bf16x8*)(gh + idx * 8);
        sgl[i] = *(const bf16x8*)(gl + idx * 8);
        int vr = idx >> 3, vcb = idx & 7;
        sgv[i] = *(const bf16x8*)(WhT + (size_t)vr * NN + (kt + 64) + vcb * 8);
      }
    }

    // ---- per-lane mask for own q-row: 64 bits ----
    const uint2 mm = *(const uint2*)(pk + (size_t)prow * 256 + (kt >> 5));

    // ---- S^T = K.Q over 2 key-32 tiles, 3-term hi/lo, K from LDS ----
    f32x16 s0, s1;
#pragma unroll
    for (int e = 0; e < 16; ++e) { s0[e] = 0.f; s1[e] = 0.f; }
#pragma unroll
    for (int st = 0; st < 8; ++st) {
      const int cb = st * 2 + h;
      const int o0 = lq * 128 + ((cb ^ (lq & 7)) * 8);
      bf16x8 ah = *(const bf16x8*)&Kh[o0];
      bf16x8 al = *(const bf16x8*)&Kl[o0];
      s0 = __builtin_amdgcn_mfma_f32_32x32x16_bf16(ah, qh[st], s0, 0, 0, 0);
      s0 = __builtin_amdgcn_mfma_f32_32x32x16_bf16(ah, ql[st], s0, 0, 0, 0);
      s0 = __builtin_amdgcn_mfma_f32_32x32x16_bf16(al, qh[st], s0, 0, 0, 0);
      const int r1 = 32 + lq;
      const int o1 = r1 * 128 + ((cb ^ (r1 & 7)) * 8);
      bf16x8 bh = *(const bf16x8*)&Kh[o1];
      bf16x8 bl = *(const bf16x8*)&Kl[o1];
      s1 = __builtin_amdgcn_mfma_f32_32x32x16_bf16(bh, qh[st], s1, 0, 0, 0);
      s1 = __builtin_amdgcn_mfma_f32_32x32x16_bf16(bh, ql[st], s1, 0, 0, 0);
      s1 = __builtin_amdgcn_mfma_f32_32x32x16_bf16(bl, qh[st], s1, 0, 0, 0);
    }

    // ---- in-lane masked online softmax (one q per lane) ----
    float rmx = -1e30f;
#pragma unroll
    for (int rg = 0; rg < 16; ++rg) {
      const int sh = (rg & 3) + 8 * (rg >> 2) + 4 * h;   // key within 32-tile
      rmx = fmaxf(rmx, ((mm.x >> sh) & 1u) ? s0[rg] : -1e30f);
      rmx = fmaxf(rmx, ((mm.y >> sh) & 1u) ? s1[rg] : -1e30f);
    }
    rmx = fmaxf(rmx, __shfl_xor(rmx, 32));
    const float nm = fmaxf(m, rmx);
    const float sc = __expf(m - nm);
    m = nm;
    float psum = 0.f;
    unsigned pw[16];                       // word k: regs 2k,2k+1 (ktile0: 0-7, ktile1: 8-15)
#pragma unroll
    for (int kk = 0; kk < 8; ++kk) {
      const int rgA = 2 * kk, rgB = 2 * kk + 1;
      const int shA = (rgA & 3) + 8 * (rgA >> 2) + 4 * h;
      const int shB = (rgB & 3) + 8 * (rgB >> 2) + 4 * h;
      float pA0 = ((mm.x >> shA) & 1u) ? __expf(s0[rgA] - m) : 0.f;
      float pB0 = ((mm.x >> shB) & 1u) ? __expf(s0[rgB] - m) : 0.f;
      ushortT qA0 = f2bf(pA0), qB0 = f2bf(pB0);
      psum += bf2f(qA0); psum += bf2f(qB0);
      pw[kk] = (unsigned)qA0 | ((unsigned)qB0 << 16);
      float pA1 = ((mm.y >> shA) & 1u) ? __expf(s1[rgA] - m) : 0.f;
      float pB1 = ((mm.y >> shB) & 1u) ? __expf(s1[rgB] - m) : 0.f;
      ushortT qA1 = f2bf(pA1), qB1 = f2bf(pB1);
      psum += bf2f(qA1); psum += bf2f(qB1);
      pw[8 + kk] = (unsigned)qA1 | ((unsigned)qB1 << 16);
    }
    psum += __shfl_xor(psum, 32);
    lr = lr * sc + psum;

    // ---- build P^T B-frags via one xor-32 exchange per word ----
    bf16x8 pa[4];
#pragma unroll
    for (int s = 0; s < 4; ++s) {
      const unsigned g0 = pw[4 * s], g1 = pw[4 * s + 1];
      const unsigned g2 = pw[4 * s + 2], g3 = pw[4 * s + 3];
      const unsigned k0 = h ? g2 : g0, k1 = h ? g3 : g1;    // own-half words
      const unsigned x0 = h ? g0 : g2, x1 = h ? g1 : g3;    // words to send
      const unsigned r0 = (unsigned)__shfl_xor((int)x0, 32);
      const unsigned r1 = (unsigned)__shfl_xor((int)x1, 32);
      union { unsigned u[4]; bf16x8 v; } uu;
      uu.u[0] = h ? r0 : k0;   // j0-3: from half-0 lane
      uu.u[1] = h ? r1 : k1;
      uu.u[2] = h ? k0 : r0;   // j4-7: from half-1 lane
      uu.u[3] = h ? k1 : r1;
      pa[s] = uu.v;
    }

    // ---- O^T rescale + PV: O^T = V^T . P^T (A from Vs LDS, B = pa) ----
#pragma unroll
    for (int ft = 0; ft < 4; ++ft)
#pragma unroll
      for (int e = 0; e < 16; ++e) O[ft][e] *= sc;
#pragma unroll
    for (int ft = 0; ft < 4; ++ft) {
      const int vr = ft * 32 + lq;
#pragma unroll
      for (int st = 0; st < 4; ++st) {
        const int cb = st * 2 + h;
        bf16x8 vb = *(const bf16x8*)&Vs[vr * 64 + ((cb ^ (vr & 7)) * 8)];
        O[ft] = __builtin_amdgcn_mfma_f32_32x32x16_bf16(vb, pa[st], O[ft], 0, 0, 0);
      }
    }

    // ---- stage the prefetched tiles into LDS for next iter ----
    if (it + 1 < te) {
      __syncthreads();                   // all waves done reading Kh/Kl/Vs
#pragma unroll
      for (int i = 0; i < 4; ++i) {
        int idx = t + 256 * i;
        int r = idx >> 4, cb = idx & 15;
        int off = r * 128 + ((cb ^ (r & 7)) * 8);
        *(bf16x8*)&Kh[off] = sgh[i];
        *(bf16x8*)&Kl[off] = sgl[i];
        int vr = idx >> 3, vcb = idx & 7;
        *(bf16x8*)&Vs[vr * 64 + ((vcb ^ (vr & 7)) * 8)] = sgv[i];
      }
      __syncthreads();                   // buffers ready
    }
  }

  // ---- epilogue: O^T regs -> Opart[q][f]; f = ft*32 + 8a + 4h + b ----
  float* Op = Opart + (size_t)chunk * 4096 * FF;
  const int qrow = q0 + w * 32 + lq;
#pragma unroll
  for (int ft = 0; ft < 4; ++ft)
#pragma unroll
    for (int a = 0; a < 4; ++a) {
      float4 v4 = {O[ft][4 * a], O[ft][4 * a + 1], O[ft][4 * a + 2], O[ft][4 * a + 3]};
      *(float4*)&Op[(size_t)qrow * FF + ft * 32 + a * 8 + h * 4] = v4;
    }
  if (h == 0) {
    mpart[chunk * 4096 + qrow] = m;
    lpart[chunk * 4096 + qrow] = lr;
  }
}

// ---------------- merge split-K partials, normalize, elu ----------------

__global__ __launch_bounds__(128) void combine_kernel(
    const float* __restrict__ Opart, const float* __restrict__ mpart,
    const float* __restrict__ lpart, const int* __restrict__ cntp,
    float* __restrict__ h) {
  const int r = blockIdx.x;
  if (r >= *cntp) return;                // junk rows never read downstream
  const int t = threadIdx.x;
  float mstar = -1e30f;
#pragma unroll
  for (int c = 0; c < NSPLIT; ++c) mstar = fmaxf(mstar, mpart[c * 4096 + r]);
  float lstar = 0.f, acc = 0.f;
#pragma unroll
  for (int c = 0; c < NSPLIT; ++c) {
    float wgt = __expf(mpart[c * 4096 + r] - mstar);
    lstar += wgt * lpart[c * 4096 + r];
    acc += wgt * Opart[((size_t)c * 4096 + r) * FF + t];
  }
  float v = acc / fmaxf(lstar, 1e-30f);
  h[r * FF + t] = v > 0.f ? v : expm1f(v);
}

// ---------------- gather by x, L2-normalize ----------------

__global__ __launch_bounds__(128) void out_kernel(const int* __restrict__ x,
                                                  const int* __restrict__ slot,
                                                  const float* __restrict__ h,
                                                  float* __restrict__ out) {
  const int b = blockIdx.x, t = threadIdx.x;
  const int s = slot[x[b]];
  float v = h[s * FF + t];
  float ss = v * v;
#pragma unroll
  for (int wd = 1; wd <= 32; wd <<= 1) ss += __shfl_xor(ss, wd);
  __shared__ float red[2];
  if ((t & 63) == 0) red[t >> 6] = ss;
  __syncthreads();
  float tot = red[0] + red[1];
  float scale = 1.f / fmaxf(sqrtf(tot), 1e-12f);
  out[b * FF + t] = v * scale;
}

// ---------------- launch ----------------

extern "C" void kernel_launch(void* const* d_in, const int* in_sizes, int n_in,
                              void* d_out, int out_size, void* d_ws, size_t ws_size,
                              hipStream_t stream) {
  const int*   x   = (const int*)d_in[0];
  const int*   adj = (const int*)d_in[1];
  const float* emb = (const float*)d_in[2];
  const float* W   = (const float*)d_in[3];
  float* out = (float*)d_out;

  char* base = (char*)d_ws;                              // ~51 MB total
  ushortT* Whh = (ushortT*)(base);                       //  0 .. 2 MB
  ushortT* Whl = (ushortT*)(base + 2097152);             //  2 .. 4 MB (dead after attn)
  float*   h   = (float*)(base + 2097152);               //  aliases Whl
  ushortT* WhT = (ushortT*)(base + 4194304);             //  4 .. 6 MB
  float* Opart = (float*)(base + 6291456);               //  6 .. 46.1 MB (19 chunks)
  float* mpart = (float*)(base + 46137344);
  float* lpart = (float*)(base + 46448640);
  unsigned* pk = (unsigned*)(base + 46759936);           //  4 MB packed adj bits
  int*   flags = (int*)(base + 50954240);
  int*   list  = (int*)(base + 50987008);
  int*   slot  = (int*)(base + 51019776);
  int*   cnt   = (int*)(base + 51052544);
  (void)in_sizes; (void)n_in; (void)out_size; (void)ws_size;

  hipLaunchKernelGGL(init_kernel,      dim3(NN / 256), dim3(256), 0, stream, flags, cnt);
  hipLaunchKernelGGL(scatter_kernel,   dim3(BB / 256), dim3(256), 0, stream, x, flags);
  hipLaunchKernelGGL(compact_kernel,   dim3(NN / 256), dim3(256), 0, stream, flags, cnt, list, slot);
  hipLaunchKernelGGL(pack_kernel,      dim3(4096 * 4), dim3(256), 0, stream, adj, list, cnt, pk);
  hipLaunchKernelGGL(wh_kernel,        dim3(NN / 32),  dim3(256), 0, stream, emb, W, Whh, Whl);
  hipLaunchKernelGGL(transpose_kernel, dim3((NN / 64) * 2), dim3(256), 0, stream, Whh, WhT);
  hipLaunchKernelGGL(attn_kernel,      dim3((BB / 128) * NSPLIT), dim3(256), 0, stream,
                     Whh, Whl, WhT, pk, list, cnt, Opart, mpart, lpart);
  hipLaunchKernelGGL(combine_kernel,   dim3(4096), dim3(128), 0, stream, Opart, mpart, lpart, cnt, h);
  hipLaunchKernelGGL(out_kernel,       dim3(BB),   dim3(128), 0, stream, x, slot, h, out);
}